// Round 5
// baseline (290.768 us; speedup 1.0000x reference)
//
#include <hip/hip_runtime.h>
#include <hip/hip_bf16.h>

#define D 512
#define BM 128
#define BN 128
#define BK 32
#define SB 512          // elements per scan block

typedef __attribute__((ext_vector_type(8))) short bf16x8;
typedef __attribute__((ext_vector_type(4))) float f32x4;

__device__ __forceinline__ unsigned short bf16_rne(float f) {
    union { float f; unsigned u; } v; v.f = f;
    return (unsigned short)((v.u + 0x7FFFu + ((v.u >> 16) & 1u)) >> 16);
}

__device__ __forceinline__ float bf2f(short s) {
    union { unsigned u; float f; } v;
    v.u = ((unsigned)(unsigned short)s) << 16;
    return v.f;
}

__device__ __forceinline__ void gload16(const void* g, void* l) {
    __builtin_amdgcn_global_load_lds(
        (const __attribute__((address_space(1))) void*)g,
        (__attribute__((address_space(3))) void*)l,
        16, 0, 0);
}

// ---------------- W fp32->bf16 conversion fused with degree histogram ----------------
__global__ __launch_bounds__(256) void prep_kernel(const float* __restrict__ W,
                                                   unsigned short* __restrict__ wb,
                                                   const int* __restrict__ dst, int E,
                                                   int* __restrict__ cnt) {
    const int b = blockIdx.x;
    const int t = threadIdx.x;
    if (b < 512) {
        const int i = b * 256 + t;
        float2 v = ((const float2*)W)[i];
        unsigned r = ((unsigned)bf16_rne(v.x)) | (((unsigned)bf16_rne(v.y)) << 16);
        ((unsigned*)wb)[i] = r;
    } else {
        const int e = (b - 512) * 256 + t;
        if (e < E) atomicAdd(&cnt[dst[e]], 1);
    }
}

// ---------------- CSR build: 2-kernel scan + sort ----------------

__global__ __launch_bounds__(256) void scan_reduce_kernel(const int* __restrict__ cnt, int M,
                                                          int* __restrict__ bsum) {
    const int t = threadIdx.x;
    const int i0 = blockIdx.x * SB + t * 2;
    int v = 0;
    if (i0 < M)     v += cnt[i0];
    if (i0 + 1 < M) v += cnt[i0 + 1];
    #pragma unroll
    for (int o = 32; o > 0; o >>= 1) v += __shfl_down(v, o, 64);
    __shared__ int ws_[4];
    if ((t & 63) == 0) ws_[t >> 6] = v;
    __syncthreads();
    if (t == 0) bsum[blockIdx.x] = ws_[0] + ws_[1] + ws_[2] + ws_[3];
}

__global__ __launch_bounds__(256) void scan_final_kernel(int* __restrict__ cnt, int M,
                                                         const int* __restrict__ bsum, int NB,
                                                         int* __restrict__ offsets) {
    __shared__ int sb[256];
    __shared__ int s[256];
    const int t = threadIdx.x;

    int bv = (t < NB) ? bsum[t] : 0;
    sb[t] = bv;
    __syncthreads();
    #pragma unroll
    for (int o = 1; o < 256; o <<= 1) {
        int u = (t >= o) ? sb[t - o] : 0;
        __syncthreads();
        sb[t] += u;
        __syncthreads();
    }
    if (blockIdx.x == 0 && t == 255) offsets[M] = sb[255];
    const int bexcl = (blockIdx.x > 0) ? sb[blockIdx.x - 1] : 0;

    const int base = blockIdx.x * SB + t * 2;
    int a = (base < M) ? cnt[base] : 0;
    int b = (base + 1 < M) ? cnt[base + 1] : 0;
    const int tsum = a + b;
    s[t] = tsum;
    __syncthreads();
    #pragma unroll
    for (int o = 1; o < 256; o <<= 1) {
        int u = (t >= o) ? s[t - o] : 0;
        __syncthreads();
        s[t] += u;
        __syncthreads();
    }
    const int excl = s[t] - tsum + bexcl;
    if (base < M)     { offsets[base] = excl;         cnt[base] = excl; }
    if (base + 1 < M) { offsets[base + 1] = excl + a; cnt[base + 1] = excl + a; }
}

__global__ __launch_bounds__(256) void sort_kernel(const int* __restrict__ src,
                                                   const int* __restrict__ dst, int E,
                                                   int* __restrict__ cursor,
                                                   int* __restrict__ sorted_src) {
    int e = blockIdx.x * 256 + threadIdx.x;
    if (e < E) {
        int pos = atomicAdd(&cursor[dst[e]], 1);
        sorted_src[pos] = src[e];
    }
}

// ---------------- GEMM first: Y = src_h @ wb^T, Y stored bf16 ----------------
// Algebraic reorder: segment_sum(msgs) @ W^T == segment_sum(msgs @ W^T), so the
// dense GEMM runs on src_h directly (streaming reads) and the random gather
// afterwards touches bf16 rows (half the bytes). A is fp32: reg-staged with
// fused fp32->bf16 conversion and per-lane swizzled ds_write_b128 (same XOR
// scheme as the verified DMA layout). B (wb, bf16) keeps global_load_lds.
// R4's issue-early/drain-late pipeline preserved: next-tile loads (A->regs,
// B->LDS) are issued BEFORE the MFMA phase; __syncthreads() after does the
// warm drain. ds_write(next) after MFMA(cur) is safe: different buffer.
__global__ __launch_bounds__(256) void gemm_kernel(const float* __restrict__ A,
                                                   const unsigned short* __restrict__ B,
                                                   unsigned short* __restrict__ Y,
                                                   int M, int MB_tiles) {
    __shared__ __align__(16) unsigned short As[2 * BM * BK];   // 16 KB
    __shared__ __align__(16) unsigned short Bs[2 * BN * BK];   // 16 KB

    const int L = blockIdx.x;
    const int mb = (L >> 5) * 8 + (L & 7);   // blocks differing in nb differ by 8 -> same XCD
    const int nb = (L >> 3) & 3;
    if (mb >= MB_tiles) return;
    const int m0 = mb * BM;
    const int n0 = nb * BN;

    const int t = threadIdx.x;
    const int lane = t & 63;
    const int wave = t >> 6;
    const int wm = wave >> 1;
    const int wn = wave & 1;
    const int quad = lane >> 4;
    const int lr = lane & 15;

    // staging: thread t owns LDS slots t*16B (row t>>2) and 2048+t*16B (row+64);
    // global k-chunk for that slot: kc = (t&3) ^ ((row>>1)&3)
    const int srow = t >> 2;
    const int scol = ((t & 3) ^ ((t >> 3) & 3)) * 8;
    const int arow0 = min(m0 + srow, M - 1);
    const int arow1 = min(m0 + 64 + srow, M - 1);
    const float* ag0 = A + (size_t)arow0 * D + scol;
    const float* ag1 = A + (size_t)arow1 * D + scol;
    const unsigned short* bg0 = B + (size_t)(n0 + srow) * D + scol;
    const unsigned short* bg1 = B + (size_t)(n0 + 64 + srow) * D + scol;

    // fragment read swizzle: slot = quad ^ ((r>>1)&3); r%16 == lr -> lane-only
    const int fsw = (quad ^ ((lr >> 1) & 3)) * 8;

    f32x4 acc[4][4] = {};

    float4 p00, p01, p10, p11;

    // prologue: tile 0
    p00 = *(const float4*)(ag0);     p01 = *(const float4*)(ag0 + 4);
    p10 = *(const float4*)(ag1);     p11 = *(const float4*)(ag1 + 4);
    gload16(bg0, Bs + t * 8);
    gload16(bg1, Bs + 2048 + t * 8);
    {
        union { bf16x8 v; unsigned short u[8]; } w0, w1;
        w0.u[0] = bf16_rne(p00.x); w0.u[1] = bf16_rne(p00.y);
        w0.u[2] = bf16_rne(p00.z); w0.u[3] = bf16_rne(p00.w);
        w0.u[4] = bf16_rne(p01.x); w0.u[5] = bf16_rne(p01.y);
        w0.u[6] = bf16_rne(p01.z); w0.u[7] = bf16_rne(p01.w);
        w1.u[0] = bf16_rne(p10.x); w1.u[1] = bf16_rne(p10.y);
        w1.u[2] = bf16_rne(p10.z); w1.u[3] = bf16_rne(p10.w);
        w1.u[4] = bf16_rne(p11.x); w1.u[5] = bf16_rne(p11.y);
        w1.u[6] = bf16_rne(p11.z); w1.u[7] = bf16_rne(p11.w);
        *(bf16x8*)&As[t * 8] = w0.v;
        *(bf16x8*)&As[2048 + t * 8] = w1.v;
    }
    __syncthreads();

    for (int kt = 0; kt < 16; ++kt) {
        const int cur = (kt & 1) * 4096;
        const int nxt = 4096 - cur;
        if (kt + 1 < 16) {
            const int k0n = (kt + 1) * BK;
            p00 = *(const float4*)(ag0 + k0n); p01 = *(const float4*)(ag0 + k0n + 4);
            p10 = *(const float4*)(ag1 + k0n); p11 = *(const float4*)(ag1 + k0n + 4);
            gload16(bg0 + k0n, Bs + nxt + t * 8);
            gload16(bg1 + k0n, Bs + nxt + 2048 + t * 8);
        }

        bf16x8 af[4], bfr[4];
        #pragma unroll
        for (int i = 0; i < 4; ++i) {
            af[i]  = *(const bf16x8*)&As[cur + (wm * 64 + i * 16 + lr) * BK + fsw];
            bfr[i] = *(const bf16x8*)&Bs[cur + (wn * 64 + i * 16 + lr) * BK + fsw];
        }
        #pragma unroll
        for (int i = 0; i < 4; ++i)
            #pragma unroll
            for (int j = 0; j < 4; ++j)
                acc[i][j] = __builtin_amdgcn_mfma_f32_16x16x32_bf16(bfr[j], af[i], acc[i][j], 0, 0, 0);

        if (kt + 1 < 16) {
            union { bf16x8 v; unsigned short u[8]; } w0, w1;
            w0.u[0] = bf16_rne(p00.x); w0.u[1] = bf16_rne(p00.y);
            w0.u[2] = bf16_rne(p00.z); w0.u[3] = bf16_rne(p00.w);
            w0.u[4] = bf16_rne(p01.x); w0.u[5] = bf16_rne(p01.y);
            w0.u[6] = bf16_rne(p01.z); w0.u[7] = bf16_rne(p01.w);
            w1.u[0] = bf16_rne(p10.x); w1.u[1] = bf16_rne(p10.y);
            w1.u[2] = bf16_rne(p10.z); w1.u[3] = bf16_rne(p10.w);
            w1.u[4] = bf16_rne(p11.x); w1.u[5] = bf16_rne(p11.y);
            w1.u[6] = bf16_rne(p11.z); w1.u[7] = bf16_rne(p11.w);
            *(bf16x8*)&As[nxt + t * 8] = w0.v;
            *(bf16x8*)&As[nxt + 2048 + t * 8] = w1.v;
            __syncthreads();
        }
    }

    // transposed epilogue: lane holds 4 consecutive cols per acc[i][j] -> ushort4
    #pragma unroll
    for (int i = 0; i < 4; ++i) {
        const int row = m0 + wm * 64 + i * 16 + lr;
        if (row >= M) continue;
        #pragma unroll
        for (int j = 0; j < 4; ++j) {
            const int colb = n0 + wn * 64 + j * 16 + quad * 4;
            ushort4 o;
            o.x = bf16_rne(acc[i][j][0]);
            o.y = bf16_rne(acc[i][j][1]);
            o.z = bf16_rne(acc[i][j][2]);
            o.w = bf16_rne(acc[i][j][3]);
            *(ushort4*)(Y + (size_t)row * D + colb) = o;
        }
    }
}

// ---------------- gather second: out[d] = sum_{e in d} Y[src[e]] + bias ----------------
// wave-per-node, 4 nodes/block, edge-batched 4/2/1. Rows are now 1 KB bf16:
// one bf16x8 (16B) per lane per edge -- half the logical bytes of the fp32
// gather this replaces. fp32 accumulate, fp32 out write.
__global__ __launch_bounds__(256) void gather_kernel(const unsigned short* __restrict__ Y,
                                                     const int* __restrict__ offsets,
                                                     const int* __restrict__ sorted_src,
                                                     const float* __restrict__ bias,
                                                     float* __restrict__ out, int M) {
    const int wv = threadIdx.x >> 6;
    const int lane = threadIdx.x & 63;
    const int d = blockIdx.x * 4 + wv;
    if (d >= M) return;
    const int beg = offsets[d];
    const int end = offsets[d + 1];
    const bf16x8* yb = (const bf16x8*)Y;      // row s = yb + s*64 (+lane)

    const float4 b0 = *(const float4*)(bias + lane * 8);
    const float4 b1 = *(const float4*)(bias + lane * 8 + 4);
    float a0 = b0.x, a1 = b0.y, a2 = b0.z, a3 = b0.w;
    float a4 = b1.x, a5 = b1.y, a6 = b1.z, a7 = b1.w;

    int e = beg;
    for (; e + 4 <= end; e += 4) {
        const int s0 = sorted_src[e];
        const int s1 = sorted_src[e + 1];
        const int s2 = sorted_src[e + 2];
        const int s3 = sorted_src[e + 3];
        bf16x8 r0 = yb[(size_t)s0 * 64 + lane];
        bf16x8 r1 = yb[(size_t)s1 * 64 + lane];
        bf16x8 r2 = yb[(size_t)s2 * 64 + lane];
        bf16x8 r3 = yb[(size_t)s3 * 64 + lane];
        a0 += bf2f(r0[0]) + bf2f(r1[0]) + bf2f(r2[0]) + bf2f(r3[0]);
        a1 += bf2f(r0[1]) + bf2f(r1[1]) + bf2f(r2[1]) + bf2f(r3[1]);
        a2 += bf2f(r0[2]) + bf2f(r1[2]) + bf2f(r2[2]) + bf2f(r3[2]);
        a3 += bf2f(r0[3]) + bf2f(r1[3]) + bf2f(r2[3]) + bf2f(r3[3]);
        a4 += bf2f(r0[4]) + bf2f(r1[4]) + bf2f(r2[4]) + bf2f(r3[4]);
        a5 += bf2f(r0[5]) + bf2f(r1[5]) + bf2f(r2[5]) + bf2f(r3[5]);
        a6 += bf2f(r0[6]) + bf2f(r1[6]) + bf2f(r2[6]) + bf2f(r3[6]);
        a7 += bf2f(r0[7]) + bf2f(r1[7]) + bf2f(r2[7]) + bf2f(r3[7]);
    }
    if (e + 2 <= end) {
        const int s0 = sorted_src[e];
        const int s1 = sorted_src[e + 1];
        bf16x8 r0 = yb[(size_t)s0 * 64 + lane];
        bf16x8 r1 = yb[(size_t)s1 * 64 + lane];
        a0 += bf2f(r0[0]) + bf2f(r1[0]);
        a1 += bf2f(r0[1]) + bf2f(r1[1]);
        a2 += bf2f(r0[2]) + bf2f(r1[2]);
        a3 += bf2f(r0[3]) + bf2f(r1[3]);
        a4 += bf2f(r0[4]) + bf2f(r1[4]);
        a5 += bf2f(r0[5]) + bf2f(r1[5]);
        a6 += bf2f(r0[6]) + bf2f(r1[6]);
        a7 += bf2f(r0[7]) + bf2f(r1[7]);
        e += 2;
    }
    if (e < end) {
        const int s0 = sorted_src[e];
        bf16x8 r0 = yb[(size_t)s0 * 64 + lane];
        a0 += bf2f(r0[0]); a1 += bf2f(r0[1]);
        a2 += bf2f(r0[2]); a3 += bf2f(r0[3]);
        a4 += bf2f(r0[4]); a5 += bf2f(r0[5]);
        a6 += bf2f(r0[6]); a7 += bf2f(r0[7]);
    }

    float4 o0 = {a0, a1, a2, a3};
    float4 o1 = {a4, a5, a6, a7};
    *(float4*)(out + (size_t)d * D + lane * 8) = o0;
    *(float4*)(out + (size_t)d * D + lane * 8 + 4) = o1;
}

extern "C" void kernel_launch(void* const* d_in, const int* in_sizes, int n_in,
                              void* d_out, int out_size, void* d_ws, size_t ws_size,
                              hipStream_t stream) {
    const float* src_h = (const float*)d_in[0];
    const float* W     = (const float*)d_in[1];
    const float* b     = (const float*)d_in[2];
    const int*   si    = (const int*)d_in[3];
    const int*   di    = (const int*)d_in[4];
    const int M = in_sizes[0] / D;    // 50000
    const int E = in_sizes[3];        // 150000
    const int NB = (M + SB - 1) / SB; // scan blocks (98)

    char* ws = (char*)d_ws;
    unsigned short* Y    = (unsigned short*)ws;                    // M*D*2
    unsigned short* wb   = (unsigned short*)(ws + 51200000);       // D*D*2
    int* offsets         = (int*)(ws + 51724288);                  // (M+1)*4
    int* cnt             = (int*)(ws + 51924480);                  // M*4
    int* ssrc            = (int*)(ws + 52124480);                  // E*4
    int* bsum            = (int*)(ws + 52724480);                  // NB*4

    hipMemsetAsync(cnt, 0, (size_t)M * sizeof(int), stream);
    const int HB = (E + 255) / 256;
    prep_kernel<<<dim3(512 + HB), 256, 0, stream>>>(W, wb, di, E, cnt);

    const int MB_tiles = (M + BM - 1) / BM;                 // 391
    const int ngrid = ((MB_tiles + 7) / 8) * 32;            // 8 m-tiles x 4 n-tiles per group
    gemm_kernel<<<dim3(ngrid), 256, 0, stream>>>(src_h, wb, Y, M, MB_tiles);

    scan_reduce_kernel<<<dim3(NB), 256, 0, stream>>>(cnt, M, bsum);
    scan_final_kernel<<<dim3(NB), 256, 0, stream>>>(cnt, M, bsum, NB, offsets);
    sort_kernel<<<dim3((E + 255) / 256), 256, 0, stream>>>(si, di, E, cnt, ssrc);
    gather_kernel<<<dim3((M + 3) / 4), 256, 0, stream>>>(Y, offsets, ssrc, b,
                                                         (float*)d_out, M);
}

// Round 6
// 284.938 us; speedup vs baseline: 1.0205x; 1.0205x over previous
//
#include <hip/hip_runtime.h>
#include <hip/hip_bf16.h>

#define D 512
#define BM 128
#define BN 128
#define BK 32
#define SB 512          // elements per scan block

typedef __attribute__((ext_vector_type(8))) short bf16x8;
typedef __attribute__((ext_vector_type(4))) float f32x4;

__device__ __forceinline__ unsigned short bf16_rne(float f) {
    union { float f; unsigned u; } v; v.f = f;
    return (unsigned short)((v.u + 0x7FFFu + ((v.u >> 16) & 1u)) >> 16);
}

__device__ __forceinline__ float bf2f(short s) {
    union { unsigned u; float f; } v;
    v.u = ((unsigned)(unsigned short)s) << 16;
    return v.f;
}

__device__ __forceinline__ void gload16(const void* g, void* l) {
    __builtin_amdgcn_global_load_lds(
        (const __attribute__((address_space(1))) void*)g,
        (__attribute__((address_space(3))) void*)l,
        16, 0, 0);
}

// ---------------- prep: W->bf16, src_h->bf16 (streaming), dst histogram ----------------
// blocks [0, 512)            : convert W (512*512 floats, 1 float2/thread)
// blocks [512, 512+SC)       : convert src_h (8 floats/thread, bf16x8 store)
// blocks [512+SC, 512+SC+HB) : histogram of dst indices
__global__ __launch_bounds__(256) void prep_kernel(const float* __restrict__ W,
                                                   unsigned short* __restrict__ wb,
                                                   const float* __restrict__ src_h,
                                                   unsigned short* __restrict__ srcb,
                                                   int total,  // = M*D
                                                   int SC,
                                                   const int* __restrict__ dst, int E,
                                                   int* __restrict__ cnt) {
    const int b = blockIdx.x;
    const int t = threadIdx.x;
    if (b < 512) {
        const int i = b * 256 + t;
        float2 v = ((const float2*)W)[i];
        unsigned r = ((unsigned)bf16_rne(v.x)) | (((unsigned)bf16_rne(v.y)) << 16);
        ((unsigned*)wb)[i] = r;
    } else if (b < 512 + SC) {
        const int i = (b - 512) * 256 + t;
        if (i * 8 < total) {
            float4 v0 = *(const float4*)(src_h + i * 8);
            float4 v1 = *(const float4*)(src_h + i * 8 + 4);
            union { bf16x8 v; unsigned short u[8]; } pk;
            pk.u[0] = bf16_rne(v0.x); pk.u[1] = bf16_rne(v0.y);
            pk.u[2] = bf16_rne(v0.z); pk.u[3] = bf16_rne(v0.w);
            pk.u[4] = bf16_rne(v1.x); pk.u[5] = bf16_rne(v1.y);
            pk.u[6] = bf16_rne(v1.z); pk.u[7] = bf16_rne(v1.w);
            *(bf16x8*)(srcb + i * 8) = pk.v;
        }
    } else {
        const int e = (b - 512 - SC) * 256 + t;
        if (e < E) atomicAdd(&cnt[dst[e]], 1);
    }
}

// ---------------- CSR build: 2-kernel scan + sort ----------------

__global__ __launch_bounds__(256) void scan_reduce_kernel(const int* __restrict__ cnt, int M,
                                                          int* __restrict__ bsum) {
    const int t = threadIdx.x;
    const int i0 = blockIdx.x * SB + t * 2;
    int v = 0;
    if (i0 < M)     v += cnt[i0];
    if (i0 + 1 < M) v += cnt[i0 + 1];
    #pragma unroll
    for (int o = 32; o > 0; o >>= 1) v += __shfl_down(v, o, 64);
    __shared__ int ws_[4];
    if ((t & 63) == 0) ws_[t >> 6] = v;
    __syncthreads();
    if (t == 0) bsum[blockIdx.x] = ws_[0] + ws_[1] + ws_[2] + ws_[3];
}

__global__ __launch_bounds__(256) void scan_final_kernel(int* __restrict__ cnt, int M,
                                                         const int* __restrict__ bsum, int NB,
                                                         int* __restrict__ offsets) {
    __shared__ int sb[256];
    __shared__ int s[256];
    const int t = threadIdx.x;

    int bv = (t < NB) ? bsum[t] : 0;
    sb[t] = bv;
    __syncthreads();
    #pragma unroll
    for (int o = 1; o < 256; o <<= 1) {
        int u = (t >= o) ? sb[t - o] : 0;
        __syncthreads();
        sb[t] += u;
        __syncthreads();
    }
    if (blockIdx.x == 0 && t == 255) offsets[M] = sb[255];
    const int bexcl = (blockIdx.x > 0) ? sb[blockIdx.x - 1] : 0;

    const int base = blockIdx.x * SB + t * 2;
    int a = (base < M) ? cnt[base] : 0;
    int b = (base + 1 < M) ? cnt[base + 1] : 0;
    const int tsum = a + b;
    s[t] = tsum;
    __syncthreads();
    #pragma unroll
    for (int o = 1; o < 256; o <<= 1) {
        int u = (t >= o) ? s[t - o] : 0;
        __syncthreads();
        s[t] += u;
        __syncthreads();
    }
    const int excl = s[t] - tsum + bexcl;
    if (base < M)     { offsets[base] = excl;         cnt[base] = excl; }
    if (base + 1 < M) { offsets[base + 1] = excl + a; cnt[base + 1] = excl + a; }
}

__global__ __launch_bounds__(256) void sort_kernel(const int* __restrict__ src,
                                                   const int* __restrict__ dst, int E,
                                                   int* __restrict__ cursor,
                                                   int* __restrict__ sorted_src) {
    int e = blockIdx.x * 256 + threadIdx.x;
    if (e < E) {
        int pos = atomicAdd(&cursor[dst[e]], 1);
        sorted_src[pos] = src[e];
    }
}

// ---------------- GEMM: Y = srcb @ wb^T (all bf16 in, bf16 out) ----------------
// Exact R4 pipeline: double-buffered LDS (2x16KB), all staging via
// global_load_lds DMA, stage(next) issued BEFORE the MFMA phase on cur, then
// ONE explicit vmcnt(0) + raw s_barrier per k-step -- loads fly during the
// full compute phase (counted-drain, the R4 win). XOR swizzle: LDS dest is
// lane-linear (DMA requirement); swizzle applied on the global source column;
// fragment reads use the matching lane-only slot permutation -> 2-way, free.
// MFMA operands swapped (bfr, af) so each lane holds 4 consecutive COLUMNS
// -> ushort4 stores to bf16 Y.
__global__ __launch_bounds__(256) void gemm_kernel(const unsigned short* __restrict__ A,
                                                   const unsigned short* __restrict__ B,
                                                   unsigned short* __restrict__ Y,
                                                   int M, int MB_tiles) {
    __shared__ __align__(16) unsigned short As[2 * BM * BK];   // 16 KB
    __shared__ __align__(16) unsigned short Bs[2 * BN * BK];   // 16 KB

    const int L = blockIdx.x;
    const int mb = (L >> 5) * 8 + (L & 7);   // blocks differing in nb differ by 8 -> same XCD
    const int nb = (L >> 3) & 3;
    if (mb >= MB_tiles) return;
    const int m0 = mb * BM;
    const int n0 = nb * BN;

    const int t = threadIdx.x;
    const int lane = t & 63;
    const int wave = t >> 6;
    const int wm = wave >> 1;
    const int wn = wave & 1;
    const int quad = lane >> 4;
    const int lr = lane & 15;

    // staging: thread t fills LDS offset t*16B = (row = t>>2, slot = t&3);
    // the k-chunk in that slot is kc = slot ^ ((row>>1)&3)
    const int srow = t >> 2;
    const int scol = ((t & 3) ^ ((t >> 3) & 3)) * 8;
    const int arow0 = min(m0 + srow, M - 1);
    const int arow1 = min(m0 + 64 + srow, M - 1);
    const unsigned short* ag0 = A + (size_t)arow0 * D + scol;
    const unsigned short* ag1 = A + (size_t)arow1 * D + scol;
    const unsigned short* bg0 = B + (size_t)(n0 + srow) * D + scol;
    const unsigned short* bg1 = B + (size_t)(n0 + 64 + srow) * D + scol;

    // fragment read swizzle: slot = quad ^ ((r>>1)&3); r%16 == lr -> lane-only
    const int fsw = (quad ^ ((lr >> 1) & 3)) * 8;

    f32x4 acc[4][4] = {};

    // prologue: stage tile 0 into buffer 0
    gload16(ag0, As + t * 8);
    gload16(ag1, As + 2048 + t * 8);
    gload16(bg0, Bs + t * 8);
    gload16(bg1, Bs + 2048 + t * 8);
    asm volatile("s_waitcnt vmcnt(0)" ::: "memory");
    __builtin_amdgcn_s_barrier();

    for (int kt = 0; kt < 16; ++kt) {
        const int cur = (kt & 1) * 4096;
        const int nxt = 4096 - cur;
        if (kt + 1 < 16) {
            const int k0n = (kt + 1) * BK;
            gload16(ag0 + k0n, As + nxt + t * 8);
            gload16(ag1 + k0n, As + nxt + 2048 + t * 8);
            gload16(bg0 + k0n, Bs + nxt + t * 8);
            gload16(bg1 + k0n, Bs + nxt + 2048 + t * 8);
        }

        bf16x8 af[4], bfr[4];
        #pragma unroll
        for (int i = 0; i < 4; ++i) {
            af[i]  = *(const bf16x8*)&As[cur + (wm * 64 + i * 16 + lr) * BK + fsw];
            bfr[i] = *(const bf16x8*)&Bs[cur + (wn * 64 + i * 16 + lr) * BK + fsw];
        }
        #pragma unroll
        for (int i = 0; i < 4; ++i)
            #pragma unroll
            for (int j = 0; j < 4; ++j)
                acc[i][j] = __builtin_amdgcn_mfma_f32_16x16x32_bf16(bfr[j], af[i], acc[i][j], 0, 0, 0);

        if (kt + 1 < 16) {
            asm volatile("s_waitcnt vmcnt(0)" ::: "memory");
            __builtin_amdgcn_s_barrier();
        }
    }

    // transposed epilogue: lane holds 4 consecutive cols per acc[i][j]
    #pragma unroll
    for (int i = 0; i < 4; ++i) {
        const int row = m0 + wm * 64 + i * 16 + lr;
        if (row >= M) continue;
        #pragma unroll
        for (int j = 0; j < 4; ++j) {
            const int colb = n0 + wn * 64 + j * 16 + quad * 4;
            ushort4 o;
            o.x = bf16_rne(acc[i][j][0]);
            o.y = bf16_rne(acc[i][j][1]);
            o.z = bf16_rne(acc[i][j][2]);
            o.w = bf16_rne(acc[i][j][3]);
            *(ushort4*)(Y + (size_t)row * D + colb) = o;
        }
    }
}

// ---------------- gather second: out[d] = sum_{e in d} Y[src[e]] + bias ----------------
// wave-per-node, 4 nodes/block, edge-batched 4/2/1; bf16 rows = half bytes.
__global__ __launch_bounds__(256) void gather_kernel(const unsigned short* __restrict__ Y,
                                                     const int* __restrict__ offsets,
                                                     const int* __restrict__ sorted_src,
                                                     const float* __restrict__ bias,
                                                     float* __restrict__ out, int M) {
    const int wv = threadIdx.x >> 6;
    const int lane = threadIdx.x & 63;
    const int d = blockIdx.x * 4 + wv;
    if (d >= M) return;
    const int beg = offsets[d];
    const int end = offsets[d + 1];
    const bf16x8* yb = (const bf16x8*)Y;      // row s = yb + s*64 (+lane)

    const float4 b0 = *(const float4*)(bias + lane * 8);
    const float4 b1 = *(const float4*)(bias + lane * 8 + 4);
    float a0 = b0.x, a1 = b0.y, a2 = b0.z, a3 = b0.w;
    float a4 = b1.x, a5 = b1.y, a6 = b1.z, a7 = b1.w;

    int e = beg;
    for (; e + 4 <= end; e += 4) {
        const int s0 = sorted_src[e];
        const int s1 = sorted_src[e + 1];
        const int s2 = sorted_src[e + 2];
        const int s3 = sorted_src[e + 3];
        bf16x8 r0 = yb[(size_t)s0 * 64 + lane];
        bf16x8 r1 = yb[(size_t)s1 * 64 + lane];
        bf16x8 r2 = yb[(size_t)s2 * 64 + lane];
        bf16x8 r3 = yb[(size_t)s3 * 64 + lane];
        a0 += bf2f(r0[0]) + bf2f(r1[0]) + bf2f(r2[0]) + bf2f(r3[0]);
        a1 += bf2f(r0[1]) + bf2f(r1[1]) + bf2f(r2[1]) + bf2f(r3[1]);
        a2 += bf2f(r0[2]) + bf2f(r1[2]) + bf2f(r2[2]) + bf2f(r3[2]);
        a3 += bf2f(r0[3]) + bf2f(r1[3]) + bf2f(r2[3]) + bf2f(r3[3]);
        a4 += bf2f(r0[4]) + bf2f(r1[4]) + bf2f(r2[4]) + bf2f(r3[4]);
        a5 += bf2f(r0[5]) + bf2f(r1[5]) + bf2f(r2[5]) + bf2f(r3[5]);
        a6 += bf2f(r0[6]) + bf2f(r1[6]) + bf2f(r2[6]) + bf2f(r3[6]);
        a7 += bf2f(r0[7]) + bf2f(r1[7]) + bf2f(r2[7]) + bf2f(r3[7]);
    }
    if (e + 2 <= end) {
        const int s0 = sorted_src[e];
        const int s1 = sorted_src[e + 1];
        bf16x8 r0 = yb[(size_t)s0 * 64 + lane];
        bf16x8 r1 = yb[(size_t)s1 * 64 + lane];
        a0 += bf2f(r0[0]) + bf2f(r1[0]);
        a1 += bf2f(r0[1]) + bf2f(r1[1]);
        a2 += bf2f(r0[2]) + bf2f(r1[2]);
        a3 += bf2f(r0[3]) + bf2f(r1[3]);
        a4 += bf2f(r0[4]) + bf2f(r1[4]);
        a5 += bf2f(r0[5]) + bf2f(r1[5]);
        a6 += bf2f(r0[6]) + bf2f(r1[6]);
        a7 += bf2f(r0[7]) + bf2f(r1[7]);
        e += 2;
    }
    if (e < end) {
        const int s0 = sorted_src[e];
        bf16x8 r0 = yb[(size_t)s0 * 64 + lane];
        a0 += bf2f(r0[0]); a1 += bf2f(r0[1]);
        a2 += bf2f(r0[2]); a3 += bf2f(r0[3]);
        a4 += bf2f(r0[4]); a5 += bf2f(r0[5]);
        a6 += bf2f(r0[6]); a7 += bf2f(r0[7]);
    }

    float4 o0 = {a0, a1, a2, a3};
    float4 o1 = {a4, a5, a6, a7};
    *(float4*)(out + (size_t)d * D + lane * 8) = o0;
    *(float4*)(out + (size_t)d * D + lane * 8 + 4) = o1;
}

extern "C" void kernel_launch(void* const* d_in, const int* in_sizes, int n_in,
                              void* d_out, int out_size, void* d_ws, size_t ws_size,
                              hipStream_t stream) {
    const float* src_h = (const float*)d_in[0];
    const float* W     = (const float*)d_in[1];
    const float* b     = (const float*)d_in[2];
    const int*   si    = (const int*)d_in[3];
    const int*   di    = (const int*)d_in[4];
    const int M = in_sizes[0] / D;    // 50000
    const int E = in_sizes[3];        // 150000
    const int NB = (M + SB - 1) / SB; // scan blocks (98)
    const int total = M * D;

    char* ws = (char*)d_ws;
    unsigned short* Y    = (unsigned short*)ws;                    // M*D*2      = 51,200,000
    unsigned short* srcb = (unsigned short*)(ws + 51200000);       // M*D*2      = 51,200,000
    unsigned short* wb   = (unsigned short*)(ws + 102400000);      // D*D*2      = 524,288
    int* offsets         = (int*)(ws + 102924288);                 // (M+1)*4
    int* cnt             = (int*)(ws + 103124480);                 // M*4
    int* ssrc            = (int*)(ws + 103324480);                 // E*4
    int* bsum            = (int*)(ws + 103924480);                 // NB*4

    hipMemsetAsync(cnt, 0, (size_t)M * sizeof(int), stream);
    const int SC = (total / 8 + 255) / 256;   // 12500
    const int HB = (E + 255) / 256;
    prep_kernel<<<dim3(512 + SC + HB), 256, 0, stream>>>(W, wb, src_h, srcb, total, SC,
                                                         di, E, cnt);

    const int MB_tiles = (M + BM - 1) / BM;                 // 391
    const int ngrid = ((MB_tiles + 7) / 8) * 32;            // 8 m-tiles x 4 n-tiles per group
    gemm_kernel<<<dim3(ngrid), 256, 0, stream>>>(srcb, wb, Y, M, MB_tiles);

    scan_reduce_kernel<<<dim3(NB), 256, 0, stream>>>(cnt, M, bsum);
    scan_final_kernel<<<dim3(NB), 256, 0, stream>>>(cnt, M, bsum, NB, offsets);
    sort_kernel<<<dim3((E + 255) / 256), 256, 0, stream>>>(si, di, E, cnt, ssrc);
    gather_kernel<<<dim3((M + 3) / 4), 256, 0, stream>>>(Y, offsets, ssrc, b,
                                                         (float*)d_out, M);
}

// Round 7
// 282.227 us; speedup vs baseline: 1.0303x; 1.0096x over previous
//
#include <hip/hip_runtime.h>
#include <hip/hip_bf16.h>

#define D 512
#define BM 128
#define BN 128
#define BK 64
#define SB 512          // elements per scan block

typedef __attribute__((ext_vector_type(8))) short bf16x8;
typedef __attribute__((ext_vector_type(4))) float f32x4;

__device__ __forceinline__ unsigned short bf16_rne(float f) {
    union { float f; unsigned u; } v; v.f = f;
    return (unsigned short)((v.u + 0x7FFFu + ((v.u >> 16) & 1u)) >> 16);
}

__device__ __forceinline__ float bf2f(short s) {
    union { unsigned u; float f; } v;
    v.u = ((unsigned)(unsigned short)s) << 16;
    return v.f;
}

__device__ __forceinline__ void gload16(const void* g, void* l) {
    __builtin_amdgcn_global_load_lds(
        (const __attribute__((address_space(1))) void*)g,
        (__attribute__((address_space(3))) void*)l,
        16, 0, 0);
}

// ---------------- prep: W->bf16, src_h->bf16 (streaming), dst histogram ----------------
__global__ __launch_bounds__(256) void prep_kernel(const float* __restrict__ W,
                                                   unsigned short* __restrict__ wb,
                                                   const float* __restrict__ src_h,
                                                   unsigned short* __restrict__ srcb,
                                                   int total,  // = M*D
                                                   int SC,
                                                   const int* __restrict__ dst, int E,
                                                   int* __restrict__ cnt) {
    const int b = blockIdx.x;
    const int t = threadIdx.x;
    if (b < 512) {
        const int i = b * 256 + t;
        float2 v = ((const float2*)W)[i];
        unsigned r = ((unsigned)bf16_rne(v.x)) | (((unsigned)bf16_rne(v.y)) << 16);
        ((unsigned*)wb)[i] = r;
    } else if (b < 512 + SC) {
        const int i = (b - 512) * 256 + t;
        if (i * 8 < total) {
            float4 v0 = *(const float4*)(src_h + i * 8);
            float4 v1 = *(const float4*)(src_h + i * 8 + 4);
            union { bf16x8 v; unsigned short u[8]; } pk;
            pk.u[0] = bf16_rne(v0.x); pk.u[1] = bf16_rne(v0.y);
            pk.u[2] = bf16_rne(v0.z); pk.u[3] = bf16_rne(v0.w);
            pk.u[4] = bf16_rne(v1.x); pk.u[5] = bf16_rne(v1.y);
            pk.u[6] = bf16_rne(v1.z); pk.u[7] = bf16_rne(v1.w);
            *(bf16x8*)(srcb + i * 8) = pk.v;
        }
    } else {
        const int e = (b - 512 - SC) * 256 + t;
        if (e < E) atomicAdd(&cnt[dst[e]], 1);
    }
}

// ---------------- CSR build: 2-kernel scan + sort ----------------

__global__ __launch_bounds__(256) void scan_reduce_kernel(const int* __restrict__ cnt, int M,
                                                          int* __restrict__ bsum) {
    const int t = threadIdx.x;
    const int i0 = blockIdx.x * SB + t * 2;
    int v = 0;
    if (i0 < M)     v += cnt[i0];
    if (i0 + 1 < M) v += cnt[i0 + 1];
    #pragma unroll
    for (int o = 32; o > 0; o >>= 1) v += __shfl_down(v, o, 64);
    __shared__ int ws_[4];
    if ((t & 63) == 0) ws_[t >> 6] = v;
    __syncthreads();
    if (t == 0) bsum[blockIdx.x] = ws_[0] + ws_[1] + ws_[2] + ws_[3];
}

__global__ __launch_bounds__(256) void scan_final_kernel(int* __restrict__ cnt, int M,
                                                         const int* __restrict__ bsum, int NB,
                                                         int* __restrict__ offsets) {
    __shared__ int sb[256];
    __shared__ int s[256];
    const int t = threadIdx.x;

    int bv = (t < NB) ? bsum[t] : 0;
    sb[t] = bv;
    __syncthreads();
    #pragma unroll
    for (int o = 1; o < 256; o <<= 1) {
        int u = (t >= o) ? sb[t - o] : 0;
        __syncthreads();
        sb[t] += u;
        __syncthreads();
    }
    if (blockIdx.x == 0 && t == 255) offsets[M] = sb[255];
    const int bexcl = (blockIdx.x > 0) ? sb[blockIdx.x - 1] : 0;

    const int base = blockIdx.x * SB + t * 2;
    int a = (base < M) ? cnt[base] : 0;
    int b = (base + 1 < M) ? cnt[base + 1] : 0;
    const int tsum = a + b;
    s[t] = tsum;
    __syncthreads();
    #pragma unroll
    for (int o = 1; o < 256; o <<= 1) {
        int u = (t >= o) ? s[t - o] : 0;
        __syncthreads();
        s[t] += u;
        __syncthreads();
    }
    const int excl = s[t] - tsum + bexcl;
    if (base < M)     { offsets[base] = excl;         cnt[base] = excl; }
    if (base + 1 < M) { offsets[base + 1] = excl + a; cnt[base + 1] = excl + a; }
}

__global__ __launch_bounds__(256) void sort_kernel(const int* __restrict__ src,
                                                   const int* __restrict__ dst, int E,
                                                   int* __restrict__ cursor,
                                                   int* __restrict__ sorted_src) {
    int e = blockIdx.x * 256 + threadIdx.x;
    if (e < E) {
        int pos = atomicAdd(&cursor[dst[e]], 1);
        sorted_src[pos] = src[e];
    }
}

// ---------------- GEMM: Y = srcb @ wb^T (bf16 in, bf16 out) ----------------
// BK=64 inside the R4 counted-drain schedule: 8 k-steps of 32 MFMA each,
// double-buffered LDS (2 x 32 KB), stage(next) issued BEFORE the compute
// phase, ONE explicit vmcnt(0) + raw s_barrier per step. Doubling the
// compute phase halves the number of exposed-latency drains (16 -> 8) and
// gives each stage 2x the flight time. 64 KB LDS -> 2 blocks/CU.
// Swizzle (128B row period, 8 slots): element chunk kc of row r lives at
// slot kc ^ (r&7); DMA dest stays lane-linear, the permutation is applied
// on the GLOBAL source column; fragment reads use the matching lane-only
// slot permutation -> 2-way bank aliasing, free.
// MFMA operands swapped (bfr, af): lane holds 4 consecutive COLUMNS.
__global__ __launch_bounds__(256) void gemm_kernel(const unsigned short* __restrict__ A,
                                                   const unsigned short* __restrict__ B,
                                                   unsigned short* __restrict__ Y,
                                                   int M, int MB_tiles) {
    __shared__ __align__(16) unsigned short As[2 * BM * BK];   // 32 KB
    __shared__ __align__(16) unsigned short Bs[2 * BN * BK];   // 32 KB

    const int L = blockIdx.x;
    const int mb = (L >> 5) * 8 + (L & 7);   // 4 n-blocks of an m-tile share an XCD
    const int nb = (L >> 3) & 3;
    if (mb >= MB_tiles) return;
    const int m0 = mb * BM;
    const int n0 = nb * BN;

    const int t = threadIdx.x;
    const int lane = t & 63;
    const int wave = t >> 6;
    const int wm = wave >> 1;
    const int wn = wave & 1;
    const int quad = lane >> 4;
    const int lr = lane & 15;

    // staging: per issue q, 256 threads cover 32 rows x 8 slots (16B each);
    // global k-chunk for linear slot (t&7) of row (t>>3): kc = (t&7)^((t>>3)&7)
    const int srow = t >> 3;                               // 0..31
    const int scol = ((t & 7) ^ (srow & 7)) * 8;           // element offset in [0,64)
    const unsigned short* ag[4];
    const unsigned short* bg[4];
    #pragma unroll
    for (int q = 0; q < 4; ++q) {
        ag[q] = A + (size_t)min(m0 + q * 32 + srow, M - 1) * D + scol;
        bg[q] = B + (size_t)(n0 + q * 32 + srow) * D + scol;
    }

    // fragment read swizzle: slot = quad ^ (r&7); r%16 == lr -> lane-only
    const int fs0 = (quad ^ (lr & 7)) * 8;

    f32x4 acc[4][4] = {};

    // prologue: stage k-tile 0 into buffer 0
    #pragma unroll
    for (int q = 0; q < 4; ++q) {
        gload16(ag[q], As + q * 2048 + t * 8);
        gload16(bg[q], Bs + q * 2048 + t * 8);
    }
    asm volatile("s_waitcnt vmcnt(0)" ::: "memory");
    __builtin_amdgcn_s_barrier();

    for (int kt = 0; kt < 8; ++kt) {
        const int cur = (kt & 1) * 8192;
        const int nxt = 8192 - cur;
        if (kt + 1 < 8) {
            const int k0n = (kt + 1) * BK;
            #pragma unroll
            for (int q = 0; q < 4; ++q) {
                gload16(ag[q] + k0n, As + nxt + q * 2048 + t * 8);
                gload16(bg[q] + k0n, Bs + nxt + q * 2048 + t * 8);
            }
        }

        #pragma unroll
        for (int kk = 0; kk < 2; ++kk) {
            const int fs = fs0 ^ (kk << 5);
            bf16x8 af[4], bfr[4];
            #pragma unroll
            for (int i = 0; i < 4; ++i) {
                af[i]  = *(const bf16x8*)&As[cur + (wm * 64 + i * 16 + lr) * BK + fs];
                bfr[i] = *(const bf16x8*)&Bs[cur + (wn * 64 + i * 16 + lr) * BK + fs];
            }
            #pragma unroll
            for (int i = 0; i < 4; ++i)
                #pragma unroll
                for (int j = 0; j < 4; ++j)
                    acc[i][j] = __builtin_amdgcn_mfma_f32_16x16x32_bf16(bfr[j], af[i], acc[i][j], 0, 0, 0);
        }

        if (kt + 1 < 8) {
            asm volatile("s_waitcnt vmcnt(0)" ::: "memory");
            __builtin_amdgcn_s_barrier();
        }
    }

    // transposed epilogue: lane holds 4 consecutive cols per acc[i][j]
    #pragma unroll
    for (int i = 0; i < 4; ++i) {
        const int row = m0 + wm * 64 + i * 16 + lr;
        if (row >= M) continue;
        #pragma unroll
        for (int j = 0; j < 4; ++j) {
            const int colb = n0 + wn * 64 + j * 16 + quad * 4;
            ushort4 o;
            o.x = bf16_rne(acc[i][j][0]);
            o.y = bf16_rne(acc[i][j][1]);
            o.z = bf16_rne(acc[i][j][2]);
            o.w = bf16_rne(acc[i][j][3]);
            *(ushort4*)(Y + (size_t)row * D + colb) = o;
        }
    }
}

// ---------------- gather second: out[d] = sum_{e in d} Y[src[e]] + bias ----------------
// wave-per-node, 4 nodes/block. Tail batched 3/2/1 (mean degree = 3): a
// deg-3 node now issues all 3 row loads concurrently instead of a serial
// 2-batch + 1-batch. Branches are wave-uniform (one node per wave).
__global__ __launch_bounds__(256) void gather_kernel(const unsigned short* __restrict__ Y,
                                                     const int* __restrict__ offsets,
                                                     const int* __restrict__ sorted_src,
                                                     const float* __restrict__ bias,
                                                     float* __restrict__ out, int M) {
    const int wv = threadIdx.x >> 6;
    const int lane = threadIdx.x & 63;
    const int d = blockIdx.x * 4 + wv;
    if (d >= M) return;
    const int beg = offsets[d];
    const int end = offsets[d + 1];
    const bf16x8* yb = (const bf16x8*)Y;      // row s = yb + s*64 (+lane)

    const float4 b0 = *(const float4*)(bias + lane * 8);
    const float4 b1 = *(const float4*)(bias + lane * 8 + 4);
    float a0 = b0.x, a1 = b0.y, a2 = b0.z, a3 = b0.w;
    float a4 = b1.x, a5 = b1.y, a6 = b1.z, a7 = b1.w;

    int e = beg;
    int n = end - beg;
    for (; n >= 4; n -= 4, e += 4) {
        const int s0 = sorted_src[e];
        const int s1 = sorted_src[e + 1];
        const int s2 = sorted_src[e + 2];
        const int s3 = sorted_src[e + 3];
        bf16x8 r0 = yb[(size_t)s0 * 64 + lane];
        bf16x8 r1 = yb[(size_t)s1 * 64 + lane];
        bf16x8 r2 = yb[(size_t)s2 * 64 + lane];
        bf16x8 r3 = yb[(size_t)s3 * 64 + lane];
        a0 += bf2f(r0[0]) + bf2f(r1[0]) + bf2f(r2[0]) + bf2f(r3[0]);
        a1 += bf2f(r0[1]) + bf2f(r1[1]) + bf2f(r2[1]) + bf2f(r3[1]);
        a2 += bf2f(r0[2]) + bf2f(r1[2]) + bf2f(r2[2]) + bf2f(r3[2]);
        a3 += bf2f(r0[3]) + bf2f(r1[3]) + bf2f(r2[3]) + bf2f(r3[3]);
        a4 += bf2f(r0[4]) + bf2f(r1[4]) + bf2f(r2[4]) + bf2f(r3[4]);
        a5 += bf2f(r0[5]) + bf2f(r1[5]) + bf2f(r2[5]) + bf2f(r3[5]);
        a6 += bf2f(r0[6]) + bf2f(r1[6]) + bf2f(r2[6]) + bf2f(r3[6]);
        a7 += bf2f(r0[7]) + bf2f(r1[7]) + bf2f(r2[7]) + bf2f(r3[7]);
    }
    if (n == 3) {
        const int s0 = sorted_src[e];
        const int s1 = sorted_src[e + 1];
        const int s2 = sorted_src[e + 2];
        bf16x8 r0 = yb[(size_t)s0 * 64 + lane];
        bf16x8 r1 = yb[(size_t)s1 * 64 + lane];
        bf16x8 r2 = yb[(size_t)s2 * 64 + lane];
        a0 += bf2f(r0[0]) + bf2f(r1[0]) + bf2f(r2[0]);
        a1 += bf2f(r0[1]) + bf2f(r1[1]) + bf2f(r2[1]);
        a2 += bf2f(r0[2]) + bf2f(r1[2]) + bf2f(r2[2]);
        a3 += bf2f(r0[3]) + bf2f(r1[3]) + bf2f(r2[3]);
        a4 += bf2f(r0[4]) + bf2f(r1[4]) + bf2f(r2[4]);
        a5 += bf2f(r0[5]) + bf2f(r1[5]) + bf2f(r2[5]);
        a6 += bf2f(r0[6]) + bf2f(r1[6]) + bf2f(r2[6]);
        a7 += bf2f(r0[7]) + bf2f(r1[7]) + bf2f(r2[7]);
    } else if (n == 2) {
        const int s0 = sorted_src[e];
        const int s1 = sorted_src[e + 1];
        bf16x8 r0 = yb[(size_t)s0 * 64 + lane];
        bf16x8 r1 = yb[(size_t)s1 * 64 + lane];
        a0 += bf2f(r0[0]) + bf2f(r1[0]);
        a1 += bf2f(r0[1]) + bf2f(r1[1]);
        a2 += bf2f(r0[2]) + bf2f(r1[2]);
        a3 += bf2f(r0[3]) + bf2f(r1[3]);
        a4 += bf2f(r0[4]) + bf2f(r1[4]);
        a5 += bf2f(r0[5]) + bf2f(r1[5]);
        a6 += bf2f(r0[6]) + bf2f(r1[6]);
        a7 += bf2f(r0[7]) + bf2f(r1[7]);
    } else if (n == 1) {
        const int s0 = sorted_src[e];
        bf16x8 r0 = yb[(size_t)s0 * 64 + lane];
        a0 += bf2f(r0[0]); a1 += bf2f(r0[1]);
        a2 += bf2f(r0[2]); a3 += bf2f(r0[3]);
        a4 += bf2f(r0[4]); a5 += bf2f(r0[5]);
        a6 += bf2f(r0[6]); a7 += bf2f(r0[7]);
    }

    float4 o0 = {a0, a1, a2, a3};
    float4 o1 = {a4, a5, a6, a7};
    *(float4*)(out + (size_t)d * D + lane * 8) = o0;
    *(float4*)(out + (size_t)d * D + lane * 8 + 4) = o1;
}

extern "C" void kernel_launch(void* const* d_in, const int* in_sizes, int n_in,
                              void* d_out, int out_size, void* d_ws, size_t ws_size,
                              hipStream_t stream) {
    const float* src_h = (const float*)d_in[0];
    const float* W     = (const float*)d_in[1];
    const float* b     = (const float*)d_in[2];
    const int*   si    = (const int*)d_in[3];
    const int*   di    = (const int*)d_in[4];
    const int M = in_sizes[0] / D;    // 50000
    const int E = in_sizes[3];        // 150000
    const int NB = (M + SB - 1) / SB; // scan blocks (98)
    const int total = M * D;

    char* ws = (char*)d_ws;
    unsigned short* Y    = (unsigned short*)ws;                    // M*D*2      = 51,200,000
    unsigned short* srcb = (unsigned short*)(ws + 51200000);       // M*D*2      = 51,200,000
    unsigned short* wb   = (unsigned short*)(ws + 102400000);      // D*D*2      = 524,288
    int* offsets         = (int*)(ws + 102924288);                 // (M+1)*4
    int* cnt             = (int*)(ws + 103124480);                 // M*4
    int* ssrc            = (int*)(ws + 103324480);                 // E*4
    int* bsum            = (int*)(ws + 103924480);                 // NB*4

    hipMemsetAsync(cnt, 0, (size_t)M * sizeof(int), stream);
    const int SC = (total / 8 + 255) / 256;   // 12500
    const int HB = (E + 255) / 256;
    prep_kernel<<<dim3(512 + SC + HB), 256, 0, stream>>>(W, wb, src_h, srcb, total, SC,
                                                         di, E, cnt);

    const int MB_tiles = (M + BM - 1) / BM;                 // 391
    const int ngrid = ((MB_tiles + 7) / 8) * 32;            // 8 m-tiles x 4 n-tiles per group
    gemm_kernel<<<dim3(ngrid), 256, 0, stream>>>(srcb, wb, Y, M, MB_tiles);

    scan_reduce_kernel<<<dim3(NB), 256, 0, stream>>>(cnt, M, bsum);
    scan_final_kernel<<<dim3(NB), 256, 0, stream>>>(cnt, M, bsum, NB, offsets);
    sort_kernel<<<dim3((E + 255) / 256), 256, 0, stream>>>(si, di, E, cnt, ssrc);
    gather_kernel<<<dim3((M + 3) / 4), 256, 0, stream>>>(Y, offsets, ssrc, b,
                                                         (float*)d_out, M);
}